// Round 1
// baseline (350.130 us; speedup 1.0000x reference)
//
#include <hip/hip_runtime.h>
#include <hip/hip_bf16.h>

typedef __bf16 bf16x8 __attribute__((ext_vector_type(8)));
typedef float  f32x4  __attribute__((ext_vector_type(4)));

#define SIZE_  131072
#define DIM_   128
#define BATCH_ 1024
#define KNN_   16

#define BM 256
#define BN 64

// ---------------- prep: emb -> bf16 + e_sq ----------------
__global__ __launch_bounds__(256) void prep_emb(const float* __restrict__ emb,
                                                __bf16* __restrict__ emb16,
                                                float* __restrict__ e_sq) {
    int wid  = (blockIdx.x * 256 + threadIdx.x) >> 6;   // row 0..1023
    int lane = threadIdx.x & 63;
    float2 v = *reinterpret_cast<const float2*>(emb + (size_t)wid * DIM_ + lane * 2);
    float s = v.x * v.x + v.y * v.y;
    #pragma unroll
    for (int off = 32; off; off >>= 1) s += __shfl_xor(s, off);
    union { __bf16 h[2]; unsigned int u; } pk;
    pk.h[0] = (__bf16)v.x; pk.h[1] = (__bf16)v.y;
    *reinterpret_cast<unsigned int*>(emb16 + (size_t)wid * DIM_ + lane * 2) = pk.u;
    if (lane == 0) e_sq[wid] = s;
}

// ---------------- prep: bank copy -> new_bank + b_sq ----------------
__global__ __launch_bounds__(256) void prep_bank(const float* __restrict__ bank,
                                                 float* __restrict__ newbank,
                                                 float* __restrict__ b_sq) {
    int wid  = (blockIdx.x * 256 + threadIdx.x) >> 6;   // row 0..131071
    int lane = threadIdx.x & 63;
    size_t base = (size_t)wid * DIM_ + lane * 2;
    float2 v = *reinterpret_cast<const float2*>(bank + base);
    *reinterpret_cast<float2*>(newbank + base) = v;
    float s = v.x * v.x + v.y * v.y;
    #pragma unroll
    for (int off = 32; off; off >>= 1) s += __shfl_xor(s, off);
    if (lane == 0) b_sq[wid] = s;
}

// ---------------- main GEMM + fused distance ----------------
// C[b,s] = emb[b,:] . bank[s,:]  (NT layout), bf16 MFMA 16x16x32.
// Block tile: BM=256 x BN=64, 4 waves (each 64 rows x 64 cols).
// LDS: A 256x128 bf16 (64KB) + B 64x128 bf16 (16KB), XOR-swizzled rows.
__global__ __launch_bounds__(256) void gemm_dist(const float* __restrict__ bank,
                                                 const __bf16* __restrict__ emb16,
                                                 const float* __restrict__ e_sq,
                                                 const float* __restrict__ b_sq,
                                                 float* __restrict__ out_dist,
                                                 float* __restrict__ out_dots) {
    __shared__ __bf16 lA[BM * DIM_];   // 64 KB
    __shared__ __bf16 lB[BN * DIM_];   // 16 KB
    char* lAc = (char*)lA;
    char* lBc = (char*)lB;

    // XCD-chunked swizzle: consecutive logical tiles -> same XCD (L2 reuse of B-tiles)
    int bid = blockIdx.x;                      // nwg = 8192, divisible by 8
    int logical = (bid & 7) * (8192 / 8) + (bid >> 3);
    int mt = logical & 3;                      // M fast: 4 m-tiles share one B-tile
    int nt = logical >> 2;
    int m0 = mt * BM;
    int n0 = nt * BN;
    int tid = threadIdx.x;

    // ---- stage A (contiguous bf16 rows from ws) ----
    {
        const char* src = (const char*)(emb16 + (size_t)m0 * DIM_);   // 65536 B
        #pragma unroll
        for (int i = 0; i < 16; ++i) {
            int o   = (i * 256 + tid) * 16;            // byte offset
            int row = o >> 8;                          // 256 B per row
            int so  = o ^ ((row & 7) << 4);
            *reinterpret_cast<int4*>(lAc + so) = *reinterpret_cast<const int4*>(src + o);
        }
    }
    // ---- stage B (f32 bank rows -> bf16, swizzled) ----
    {
        #pragma unroll
        for (int i = 0; i < 4; ++i) {
            int p   = i * 256 + tid;                   // 0..1023, 8 f32 each
            int row = p >> 4;                          // 16 chunks of 8 per row
            int k0  = (p & 15) * 8;
            const float4* s4 = reinterpret_cast<const float4*>(bank + (size_t)(n0 + row) * DIM_ + k0);
            float4 a = s4[0], b = s4[1];
            union { __bf16 h[8]; int4 v; } pk;
            pk.h[0] = (__bf16)a.x; pk.h[1] = (__bf16)a.y; pk.h[2] = (__bf16)a.z; pk.h[3] = (__bf16)a.w;
            pk.h[4] = (__bf16)b.x; pk.h[5] = (__bf16)b.y; pk.h[6] = (__bf16)b.z; pk.h[7] = (__bf16)b.w;
            int o  = (row << 8) + k0 * 2;
            int so = o ^ ((row & 7) << 4);
            *reinterpret_cast<int4*>(lBc + so) = pk.v;
        }
    }
    __syncthreads();

    int wv   = tid >> 6;        // wave 0..3 -> rows wv*64..
    int lane = tid & 63;
    int lr   = lane & 15;       // fragment row/col
    int lkb  = (lane >> 4) * 8; // k sub-offset

    f32x4 acc[4][4] = {};

    #pragma unroll
    for (int ks = 0; ks < 4; ++ks) {
        int kk = ks * 32 + lkb;
        bf16x8 af[4], bf[4];
        #pragma unroll
        for (int mr = 0; mr < 4; ++mr) {
            int row = wv * 64 + mr * 16 + lr;
            int o   = (row << 8) + kk * 2;
            af[mr]  = *reinterpret_cast<const bf16x8*>(lAc + (o ^ ((row & 7) << 4)));
        }
        #pragma unroll
        for (int nc = 0; nc < 4; ++nc) {
            int row = nc * 16 + lr;
            int o   = (row << 8) + kk * 2;
            bf[nc]  = *reinterpret_cast<const bf16x8*>(lBc + (o ^ ((row & 7) << 4)));
        }
        #pragma unroll
        for (int mr = 0; mr < 4; ++mr)
            #pragma unroll
            for (int nc = 0; nc < 4; ++nc)
                acc[mr][nc] = __builtin_amdgcn_mfma_f32_16x16x32_bf16(af[mr], bf[nc], acc[mr][nc], 0, 0, 0);
    }

    // ---- epilogue: dist = sqrt(max(e2+b2-2d,0)), store both outputs ----
    int rgrp = lane >> 4;
    float bs[4];
    #pragma unroll
    for (int nc = 0; nc < 4; ++nc) bs[nc] = b_sq[n0 + nc * 16 + lr];
    float es[4][4];
    #pragma unroll
    for (int mr = 0; mr < 4; ++mr)
        #pragma unroll
        for (int j = 0; j < 4; ++j)
            es[mr][j] = e_sq[m0 + wv * 64 + mr * 16 + rgrp * 4 + j];

    #pragma unroll
    for (int mr = 0; mr < 4; ++mr) {
        #pragma unroll
        for (int j = 0; j < 4; ++j) {
            int grow = m0 + wv * 64 + mr * 16 + rgrp * 4 + j;
            size_t rb = (size_t)grow * SIZE_;
            #pragma unroll
            for (int nc = 0; nc < 4; ++nc) {
                int gcol = n0 + nc * 16 + lr;
                float d  = acc[mr][nc][j];
                float arg = es[mr][j] + bs[nc] - 2.0f * d;
                out_dist[rb + gcol] = sqrtf(fmaxf(arg, 0.0f));
                out_dots[rb + gcol] = d;
            }
        }
    }
}

// ---------------- scatter rows (last occurrence wins) ----------------
__global__ __launch_bounds__(128) void scatter_rows(const float* __restrict__ dmem,
                                                    const int* __restrict__ upd,
                                                    float* __restrict__ newbank) {
    int i = blockIdx.x;
    int idx = upd[i];
    __shared__ int dup;
    if (threadIdx.x == 0) dup = 0;
    __syncthreads();
    for (int j = i + 1 + threadIdx.x; j < BATCH_; j += 128)
        if (upd[j] == idx) dup = 1;
    __syncthreads();
    if (dup) return;
    newbank[(size_t)idx * DIM_ + threadIdx.x] = dmem[(size_t)i * DIM_ + threadIdx.x];
}

// ---------------- knn dots (one wave per (b,k), exact f32) ----------------
__global__ __launch_bounds__(256) void knn_kernel(const float* __restrict__ bank,
                                                  const float* __restrict__ emb,
                                                  const int* __restrict__ idxs,
                                                  float* __restrict__ knn) {
    int wid  = (blockIdx.x * 256 + threadIdx.x) >> 6;  // 0..16383
    int lane = threadIdx.x & 63;
    int b    = wid >> 4;
    int idx  = idxs[wid];
    float2 br = *reinterpret_cast<const float2*>(bank + (size_t)idx * DIM_ + lane * 2);
    float2 er = *reinterpret_cast<const float2*>(emb + (size_t)b * DIM_ + lane * 2);
    float s = br.x * er.x + br.y * er.y;
    #pragma unroll
    for (int off = 32; off; off >>= 1) s += __shfl_xor(s, off);
    if (lane == 0) knn[wid] = s;
}

extern "C" void kernel_launch(void* const* d_in, const int* in_sizes, int n_in,
                              void* d_out, int out_size, void* d_ws, size_t ws_size,
                              hipStream_t stream) {
    const float* emb  = (const float*)d_in[0];
    const float* dmem = (const float*)d_in[1];
    const float* bank = (const float*)d_in[2];
    const int*   idxs = (const int*)d_in[3];
    const int*   upd  = (const int*)d_in[4];

    float* out       = (float*)d_out;
    float* out_dist  = out;
    float* out_dots  = out + (size_t)BATCH_ * SIZE_;
    float* out_knn   = out + (size_t)2 * BATCH_ * SIZE_;
    float* out_bank  = out_knn + (size_t)BATCH_ * KNN_;

    char*   ws    = (char*)d_ws;
    float*  b_sq  = (float*)ws;                        // 131072 f32 = 512 KB
    float*  e_sq  = (float*)(ws + 524288);             // 1024 f32
    __bf16* emb16 = (__bf16*)(ws + 528384);            // 1024*128 bf16 = 256 KB

    prep_emb <<<BATCH_ / 4,      256, 0, stream>>>(emb, emb16, e_sq);
    prep_bank<<<SIZE_ / 4,       256, 0, stream>>>(bank, out_bank, b_sq);
    gemm_dist<<<(BATCH_ / BM) * (SIZE_ / BN), 256, 0, stream>>>(bank, emb16, e_sq, b_sq, out_dist, out_dots);
    scatter_rows<<<BATCH_,       128, 0, stream>>>(dmem, upd, out_bank);
    knn_kernel<<<(BATCH_ * KNN_) / 4, 256, 0, stream>>>(bank, emb, idxs, out_knn);
}